// Round 13
// baseline (5229.649 us; speedup 1.0000x reference)
//
#include <hip/hip_runtime.h>
#include <math.h>

typedef unsigned short u16;
typedef _Float16 h16;
typedef _Float16 f16x8 __attribute__((ext_vector_type(8)));
typedef float f32x4 __attribute__((ext_vector_type(4)));

__device__ __forceinline__ float sigm(float x) { return 1.f / (1.f + expf(-x)); }

// ---------------- Prologue kernels ----------------

// Pack W = [Wx;Wh;Wattn] (1536 x 2048 f32) into per-colblock f16 hi/lo MFMA
// b-frag streams. Layout: [j 0..64)[ks 0..48)[cf 0..2)[l 0..64)[e 0..8)
// element = W[k = ks*32 + (l>>4)*8 + e][acol], acol = (c32>>3)*512 + j*8 + (c32&7),
// c32 = cf*16 + (l&15).  lo scaled by 2^12 (exact) to stay in fp16 normal range.
__global__ void k_pack_w(const float* __restrict__ Wx, const float* __restrict__ Wh,
                         const float* __restrict__ Wat,
                         h16* __restrict__ WhiS, h16* __restrict__ WloS) {
  unsigned idx = blockIdx.x * 256 + threadIdx.x;   // 0..3145727
  unsigned e = idx & 7, l = (idx >> 3) & 63, cf = (idx >> 9) & 1;
  unsigned t2 = idx >> 10;
  unsigned j = t2 / 48u, ks = t2 - j * 48u;
  unsigned k = ks * 32 + ((l >> 4) << 3) + e;
  unsigned c32 = cf * 16 + (l & 15);
  unsigned acol = (c32 >> 3) * 512 + j * 8 + (c32 & 7);
  float v = (k < 512) ? Wx[(size_t)k * 2048 + acol]
          : (k < 1024) ? Wh[(size_t)(k - 512) * 2048 + acol]
                       : Wat[(size_t)(k - 1024) * 2048 + acol];
  h16 hi = (h16)v;
  WhiS[idx] = hi;
  WloS[idx] = (h16)((v - (float)hi) * 4096.f);
}

// x (f32) -> xhi/xlo fp16 streams, same [n][t][k] layout
__global__ void k_xsplit(const float* __restrict__ x, h16* __restrict__ xhi,
                         h16* __restrict__ xlo) {
  size_t i = ((size_t)blockIdx.x * 256 + threadIdx.x) * 4;
  float4 v = *(const float4*)(x + i);
  union { h16 h[4]; uint2 u; } a, b;
  float vv[4] = {v.x, v.y, v.z, v.w};
#pragma unroll
  for (int e = 0; e < 4; ++e) {
    h16 hh = (h16)vv[e];
    a.h[e] = hh;
    b.h[e] = (h16)((vv[e] - (float)hh) * 4096.f);
  }
  *(uint2*)(xhi + i) = a.u;
  *(uint2*)(xlo + i) = b.u;
}

// h0 = c0 = mean_p A[n][k][p] (fp32) + fp16 hi/lo split; zero barrier words
__global__ void k_init(const float* __restrict__ Af, float* __restrict__ h32,
                       h16* __restrict__ hhi, h16* __restrict__ hlo,
                       float* __restrict__ cst, int* __restrict__ bar) {
  int idx = blockIdx.x * 256 + threadIdx.x;   // n*512 + k, 131072 total
  const float* ap = Af + (size_t)idx * 16;
  float s = 0.f;
#pragma unroll
  for (int p = 0; p < 16; ++p) s += ap[p];
  s *= 0.0625f;
  h32[idx] = s;   // time-buffer 0
  cst[idx] = s;
  h16 hh = (h16)s;
  hhi[idx] = hh;
  hlo[idx] = (h16)((s - (float)hh) * 4096.f);
  if (idx < 512) bar[idx] = 0;   // re-zeroed every launch (graph replay safe)
}

// ---------------- Grid barrier (broadcast tree, decontended) ----------------
// bar layout (ints): [leaf*16] 8 leaf counters (64B apart) | [128] root cnt |
// [160] root gen | [192 + leaf*32] 8 broadcast lines (128B apart).
// Arrive: leaf add (32/leaf) -> root add (8) -> gen add -> fence -> broadcast to
// 8 lines. Wait: poll OWN leaf's broadcast line only (32 pollers/line, s_sleep(8))
// -> no poll storm on the arrival path (R11: 37us/step stall from single-line spin).

__device__ __forceinline__ void bar_arrive(int* bar) {
  __syncthreads();   // all block work done + drains stores before the fence
  if (threadIdx.x == 0) {
    __threadfence();
    int old = __hip_atomic_fetch_add(bar + (blockIdx.x & 7) * 16, 1, __ATOMIC_RELAXED,
                                     __HIP_MEMORY_SCOPE_AGENT);
    if ((old & 31) == 31) {
      int o2 = __hip_atomic_fetch_add(bar + 128, 1, __ATOMIC_RELAXED,
                                      __HIP_MEMORY_SCOPE_AGENT);
      if ((o2 & 7) == 7) {
        int g0 = __hip_atomic_fetch_add(bar + 160, 1, __ATOMIC_RELAXED,
                                        __HIP_MEMORY_SCOPE_AGENT);
        __threadfence();
#pragma unroll
        for (int b = 0; b < 8; ++b)
          __hip_atomic_store(bar + 192 + b * 32, g0 + 1, __ATOMIC_RELEASE,
                             __HIP_MEMORY_SCOPE_AGENT);
      }
    }
  }
}

__device__ __forceinline__ void bar_wait(int* bar, int ep) {
  if (threadIdx.x == 0) {
    int* slot = bar + 192 + (blockIdx.x & 7) * 32;
    int spins = 0;
    while (__hip_atomic_load(slot, __ATOMIC_RELAXED, __HIP_MEMORY_SCOPE_AGENT) < ep) {
      __builtin_amdgcn_s_sleep(8);
      if (++spins > (1 << 15)) break;   // watchdog ~7ms: never wedge the GPU
    }
    (void)__hip_atomic_load(slot, __ATOMIC_ACQUIRE, __HIP_MEMORY_SCOPE_AGENT);
  }
  __syncthreads();
}

// ---------------- Main persistent kernel ----------------
// 256 blocks x 512 threads, 1 block/CU (134 KB LDS). Block (g = bid>>6, j = bid&63):
// rows n0..n0+63 (n0 = g*64), h-cols j*8..j*8+7 (x4 gates = 32 a-cols).
// Per-step schedule (both barriers overlapped with independent GEMM work):
//   x-GEMM || wait bar2(t-1) -> phaseA -> arrive bar1 -> h-GEMM || wait bar1
//   -> attn-GEMM -> reduce -> cell -> arrive bar2

template<bool XPRE>
__global__ __launch_bounds__(512, 2) void rnn_main(
    const float* __restrict__ Af, const float* __restrict__ bv,
    const float* __restrict__ x, const h16* __restrict__ xhi, const h16* __restrict__ xlo,
    const h16* __restrict__ WhiS, const h16* __restrict__ WloS,
    float* __restrict__ h32, h16* __restrict__ hhi, h16* __restrict__ hlo,
    h16* __restrict__ ahiB, h16* __restrict__ aloB,
    float* __restrict__ cst, float* __restrict__ out, int* __restrict__ bar) {
  __shared__ f16x8 Wlds[6144];    // [ks 48][cf 2][l 64] b-frags of Whi : 98304 B
  __shared__ float P[4 * 2112];   // 4 slots of [64 rows][33] : 33792 B (also phase-A scratch)
  __shared__ float ared[512];     // [32][16]
  __shared__ float wlds[16];

  const int tid = threadIdx.x;
  const int l = tid & 63, wv = tid >> 6;
  const int bid = blockIdx.x;
  const int g = bid >> 6, j = bid & 63;
  const int n0 = g * 64;
  const int myn = n0 + j;              // phase-A row owned by this block
  const int rA = n0 + (l & 15);        // A-frag row base
  const int klane = (l >> 4) * 8;

  // Whi slice -> LDS (persistent across all 128 steps)
  {
    const uint4* src = (const uint4*)(WhiS + (size_t)j * 49152);
    uint4* dst = (uint4*)Wlds;
    for (int i = tid; i < 6144; i += 512) dst[i] = src[i];
  }
  const h16* wloJ = WloS + (size_t)j * 49152;

  // cell-phase constants: thread -> (row rC, col qC)
  const int rC = tid >> 3, qC = tid & 7;
  const int colC = j * 8 + qC;
  const float b_i = bv[colC], b_f = bv[512 + colC], b_o = bv[1024 + colC],
              b_g = bv[1536 + colC];

  int ep = 0;
  __syncthreads();

  for (int t = 0; t < 128; ++t) {
    const int rb = t & 1, wb = rb ^ 1;
    const float* h32r = h32 + (size_t)rb * 131072;
    const h16* hhiR = hhi + (size_t)rb * 131072;
    const h16* hloR = hlo + (size_t)rb * 131072;

    f32x4 acc1[4][2], acc2[4][2];
#pragma unroll
    for (int rt = 0; rt < 4; ++rt)
#pragma unroll
      for (int cf = 0; cf < 2; ++cf) {
        acc1[rt][cf] = (f32x4){0.f, 0.f, 0.f, 0.f};
        acc2[rt][cf] = (f32x4){0.f, 0.f, 0.f, 0.f};
      }

    auto kstep = [&](int ksg) {
      const f16x8 bh0 = Wlds[(ksg * 2 + 0) * 64 + l];
      const f16x8 bh1 = Wlds[(ksg * 2 + 1) * 64 + l];
      const f16x8 bl0 = *(const f16x8*)(wloJ + ((size_t)(ksg * 2 + 0) * 64 + l) * 8);
      const f16x8 bl1 = *(const f16x8*)(wloJ + ((size_t)(ksg * 2 + 1) * 64 + l) * 8);
      f16x8 Ah[4], Al[4];
      const int kg = ksg * 32;
      if (kg < 512) {
        const size_t base = ((size_t)rA * 128 + t) * 512 + kg + klane;
        if (XPRE) {
#pragma unroll
          for (int rt = 0; rt < 4; ++rt) {
            Ah[rt] = *(const f16x8*)(xhi + base + (size_t)rt * 1048576);
            Al[rt] = *(const f16x8*)(xlo + base + (size_t)rt * 1048576);
          }
        } else {
#pragma unroll
          for (int rt = 0; rt < 4; ++rt) {
            const float* xp = x + base + (size_t)rt * 1048576;
            f32x4 v0 = *(const f32x4*)xp, v1 = *(const f32x4*)(xp + 4);
            float vv[8] = {v0[0], v0[1], v0[2], v0[3], v1[0], v1[1], v1[2], v1[3]};
#pragma unroll
            for (int e = 0; e < 8; ++e) {
              h16 hh = (h16)vv[e];
              Ah[rt][e] = hh;
              Al[rt][e] = (h16)((vv[e] - (float)hh) * 4096.f);
            }
          }
        }
      } else if (kg < 1024) {
        const size_t base = (size_t)rA * 512 + (kg - 512) + klane;
#pragma unroll
        for (int rt = 0; rt < 4; ++rt) {
          Ah[rt] = *(const f16x8*)(hhiR + base + rt * 8192);
          Al[rt] = *(const f16x8*)(hloR + base + rt * 8192);
        }
      } else {
        const size_t base = (size_t)rA * 512 + (kg - 1024) + klane;
#pragma unroll
        for (int rt = 0; rt < 4; ++rt) {
          Ah[rt] = *(const f16x8*)(ahiB + base + rt * 8192);
          Al[rt] = *(const f16x8*)(aloB + base + rt * 8192);
        }
      }
#pragma unroll
      for (int rt = 0; rt < 4; ++rt) {
        acc1[rt][0] = __builtin_amdgcn_mfma_f32_16x16x32_f16(Ah[rt], bh0, acc1[rt][0], 0, 0, 0);
        acc1[rt][1] = __builtin_amdgcn_mfma_f32_16x16x32_f16(Ah[rt], bh1, acc1[rt][1], 0, 0, 0);
        acc2[rt][0] = __builtin_amdgcn_mfma_f32_16x16x32_f16(Al[rt], bh0, acc2[rt][0], 0, 0, 0);
        acc2[rt][1] = __builtin_amdgcn_mfma_f32_16x16x32_f16(Al[rt], bh1, acc2[rt][1], 0, 0, 0);
        acc2[rt][0] = __builtin_amdgcn_mfma_f32_16x16x32_f16(Ah[rt], bl0, acc2[rt][0], 0, 0, 0);
        acc2[rt][1] = __builtin_amdgcn_mfma_f32_16x16x32_f16(Ah[rt], bl1, acc2[rt][1], 0, 0, 0);
      }
    };

    // ---- x-GEMM (ksg 0..15): depends only on x — overlaps bar2(t-1) wait ----
#pragma unroll
    for (int i = 0; i < 2; ++i) kstep(wv + 8 * i);

    // ---- wait bar2 of previous step: h(t), c(t) now visible ----
    if (t > 0) bar_wait(bar, ep);

    // ---------- PHASE A: scores -> softmax -> attn (row myn), all fp32 ----------
    float Areg[16];
    {
      const f32x4* A4 = (const f32x4*)(Af + (size_t)myn * 8192 + tid * 16);
#pragma unroll
      for (int q4 = 0; q4 < 4; ++q4) {
        f32x4 v = A4[q4];
#pragma unroll
        for (int e = 0; e < 4; ++e) Areg[q4 * 4 + e] = v[e];
      }
      float hk = h32r[(size_t)myn * 512 + tid];   // thread owns k = tid
      float* SC = P;                              // [512][16] scratch
#pragma unroll
      for (int p = 0; p < 16; ++p) SC[tid * 16 + p] = hk * Areg[p];
    }
    __syncthreads();
    {
      int seg = tid >> 4, pp = tid & 15;
      float s = 0.f;
#pragma unroll
      for (int q = 0; q < 16; ++q) s += P[(seg * 16 + q) * 16 + pp];
      ared[seg * 16 + pp] = s;
    }
    __syncthreads();
    if (tid < 16) {
      float s = 0.f;
#pragma unroll
      for (int q = 0; q < 32; ++q) s += ared[q * 16 + tid];
      s *= 0.04419417382415922f;   // 1/sqrt(512)
      float m = s;
#pragma unroll
      for (int o = 8; o >= 1; o >>= 1) m = fmaxf(m, __shfl_xor(m, o, 16));
      float e = __expf(s - m);
      float se = e;
#pragma unroll
      for (int o = 8; o >= 1; o >>= 1) se += __shfl_xor(se, o, 16);
      wlds[tid] = e / se;
    }
    __syncthreads();
    {
      float av = 0.f;
#pragma unroll
      for (int p = 0; p < 16; ++p) av += Areg[p] * wlds[p];
      h16 ah = (h16)av;
      ahiB[(size_t)myn * 512 + tid] = ah;
      aloB[(size_t)myn * 512 + tid] = (h16)((av - (float)ah) * 4096.f);
    }
    // ---- arrive bar1 (attn published) ----
    ++ep;
    bar_arrive(bar);

    // ---- h-GEMM (ksg 16..31): needs h(t) only — overlaps bar1 wait ----
#pragma unroll
    for (int i = 2; i < 4; ++i) kstep(wv + 8 * i);

    // ---- wait bar1: all attn visible ----
    bar_wait(bar, ep);

    // ---- attn-GEMM (ksg 32..47) ----
#pragma unroll
    for (int i = 4; i < 6; ++i) kstep(wv + 8 * i);

    // combine hi + 2^-12 * lo-cross
    float accf[4][2][4];
#pragma unroll
    for (int rt = 0; rt < 4; ++rt)
#pragma unroll
      for (int cf = 0; cf < 2; ++cf)
#pragma unroll
        for (int rg = 0; rg < 4; ++rg)
          accf[rt][cf][rg] = acc1[rt][cf][rg] + acc2[rt][cf][rg] * (1.f / 4096.f);

    auto publish = [&](int slot) {
#pragma unroll
      for (int rt = 0; rt < 4; ++rt)
#pragma unroll
        for (int cf = 0; cf < 2; ++cf)
#pragma unroll
          for (int rg = 0; rg < 4; ++rg)
            P[slot * 2112 + (rt * 16 + (l >> 4) * 4 + rg) * 33 + cf * 16 + (l & 15)] =
                accf[rt][cf][rg];
    };
    auto addin = [&](int slot) {
#pragma unroll
      for (int rt = 0; rt < 4; ++rt)
#pragma unroll
        for (int cf = 0; cf < 2; ++cf)
#pragma unroll
          for (int rg = 0; rg < 4; ++rg)
            accf[rt][cf][rg] +=
                P[slot * 2112 + (rt * 16 + (l >> 4) * 4 + rg) * 33 + cf * 16 + (l & 15)];
    };

    if (wv >= 4) publish(wv - 4);
    __syncthreads();
    if (wv < 4) addin(wv);
    if (wv == 2) publish(2);
    if (wv == 3) publish(3);
    __syncthreads();
    if (wv == 0) addin(2);
    if (wv == 1) { addin(3); publish(1); }
    __syncthreads();
    if (wv == 0) { addin(1); publish(0); }
    __syncthreads();

    // ---------- CELL: gates (fp32) + state update, all 512 threads ----------
    {
      float ai = P[rC * 33 + qC] + b_i;
      float af_ = P[rC * 33 + 8 + qC] + b_f;
      float ao = P[rC * 33 + 16 + qC] + b_o;
      float ag = P[rC * 33 + 24 + qC] + b_g;
      float ig = sigm(ai), fg = sigm(af_), og = sigm(ao), gg = tanhf(ag);
      const size_t cix = (size_t)(n0 + rC) * 512 + colC;
      float c = cst[cix];
      float cn = fg * c + ig * gg;
      cst[cix] = cn;
      float hn = og * tanhf(cn);
      h32[(size_t)wb * 131072 + cix] = hn;
      h16 hh = (h16)hn;
      hhi[(size_t)wb * 131072 + cix] = hh;
      hlo[(size_t)wb * 131072 + cix] = (h16)((hn - (float)hh) * 4096.f);
      out[((size_t)(n0 + rC) * 128 + t) * 512 + colC] = hn;   // fp32 output
    }
    // ---- arrive bar2 (h(t+1), c published); wait happens at top of t+1 ----
    ++ep;
    bar_arrive(bar);
  }
}

// ---------------- Host launcher ----------------

extern "C" void kernel_launch(void* const* d_in, const int* in_sizes, int n_in,
                              void* d_out, int out_size, void* d_ws, size_t ws_size,
                              hipStream_t stream) {
  (void)in_sizes; (void)n_in; (void)out_size;
  const float* x   = (const float*)d_in[0];   // (256,128,512)
  const float* Af  = (const float*)d_in[1];   // (256,512,16)
  const float* Wx  = (const float*)d_in[2];   // (512,2048)
  const float* Wh  = (const float*)d_in[3];   // (512,2048)
  const float* Wat = (const float*)d_in[4];   // (512,2048)
  const float* bv  = (const float*)d_in[5];   // (2048,)
  float* out = (float*)d_out;                 // fp32 output (reference dtype)

  char* ws = (char*)d_ws;
  size_t off = 0;
  auto alloc = [&](size_t nb) {
    char* p = ws + off; off = (off + nb + 255) & ~(size_t)255; return p;
  };
  int*   bar  = (int*)alloc(2048);
  h16*   WhiS = (h16*)alloc(3145728ull * 2);
  h16*   WloS = (h16*)alloc(3145728ull * 2);
  float* h32  = (float*)alloc(262144ull * 4);
  h16*   hhi  = (h16*)alloc(262144ull * 2);
  h16*   hlo  = (h16*)alloc(262144ull * 2);
  h16*   ahiB = (h16*)alloc(131072ull * 2);
  h16*   aloB = (h16*)alloc(131072ull * 2);
  float* cst  = (float*)alloc(131072ull * 4);
  size_t base_end = off;
  h16* xhi = (h16*)alloc(16777216ull * 2);
  h16* xlo = (h16*)alloc(16777216ull * 2);
  bool xpre = (ws_size >= base_end + 2ull * 16777216ull * 2 + 4096);

  k_pack_w<<<12288, 256, 0, stream>>>(Wx, Wh, Wat, WhiS, WloS);
  k_init<<<512, 256, 0, stream>>>(Af, h32, hhi, hlo, cst, bar);

  if (xpre) {
    k_xsplit<<<16384, 256, 0, stream>>>(x, xhi, xlo);
    void* args[] = { (void*)&Af, (void*)&bv, (void*)&x, (void*)&xhi, (void*)&xlo,
                     (void*)&WhiS, (void*)&WloS, (void*)&h32, (void*)&hhi, (void*)&hlo,
                     (void*)&ahiB, (void*)&aloB, (void*)&cst, (void*)&out, (void*)&bar };
    hipError_t err = hipLaunchCooperativeKernel((void*)rnn_main<true>, dim3(256),
                                                dim3(512), args, 0, stream);
    if (err != hipSuccess) {
      (void)hipGetLastError();
      rnn_main<true><<<256, 512, 0, stream>>>(Af, bv, x, xhi, xlo, WhiS, WloS,
                                              h32, hhi, hlo, ahiB, aloB, cst, out, bar);
    }
  } else {
    void* args[] = { (void*)&Af, (void*)&bv, (void*)&x, (void*)&xhi, (void*)&xlo,
                     (void*)&WhiS, (void*)&WloS, (void*)&h32, (void*)&hhi, (void*)&hlo,
                     (void*)&ahiB, (void*)&aloB, (void*)&cst, (void*)&out, (void*)&bar };
    hipError_t err = hipLaunchCooperativeKernel((void*)rnn_main<false>, dim3(256),
                                                dim3(512), args, 0, stream);
    if (err != hipSuccess) {
      (void)hipGetLastError();
      rnn_main<false><<<256, 512, 0, stream>>>(Af, bv, x, xhi, xlo, WhiS, WloS,
                                               h32, hhi, hlo, ahiB, aloB, cst, out, bar);
    }
  }
}

// Round 14
// 2928.144 us; speedup vs baseline: 1.7860x; 1.7860x over previous
//
#include <hip/hip_runtime.h>
#include <math.h>

typedef unsigned short u16;
typedef _Float16 h16;
typedef _Float16 f16x8 __attribute__((ext_vector_type(8)));
typedef float f32x4 __attribute__((ext_vector_type(4)));

__device__ __forceinline__ float sigm(float x) { return 1.f / (1.f + expf(-x)); }

// ---------------- Prologue kernels ----------------

// Pack W = [Wx;Wh;Wattn] (1536 x 2048 f32) into per-colblock f16 hi/lo MFMA
// b-frag streams. Layout: [j 0..64)[ks 0..48)[cf 0..2)[l 0..64)[e 0..8)
// element = W[k = ks*32 + (l>>4)*8 + e][acol], acol = (c32>>3)*512 + j*8 + (c32&7),
// c32 = cf*16 + (l&15).  lo scaled by 2^12 (exact) to stay in fp16 normal range.
__global__ void k_pack_w(const float* __restrict__ Wx, const float* __restrict__ Wh,
                         const float* __restrict__ Wat,
                         h16* __restrict__ WhiS, h16* __restrict__ WloS) {
  unsigned idx = blockIdx.x * 256 + threadIdx.x;   // 0..3145727
  unsigned e = idx & 7, l = (idx >> 3) & 63, cf = (idx >> 9) & 1;
  unsigned t2 = idx >> 10;
  unsigned j = t2 / 48u, ks = t2 - j * 48u;
  unsigned k = ks * 32 + ((l >> 4) << 3) + e;
  unsigned c32 = cf * 16 + (l & 15);
  unsigned acol = (c32 >> 3) * 512 + j * 8 + (c32 & 7);
  float v = (k < 512) ? Wx[(size_t)k * 2048 + acol]
          : (k < 1024) ? Wh[(size_t)(k - 512) * 2048 + acol]
                       : Wat[(size_t)(k - 1024) * 2048 + acol];
  h16 hi = (h16)v;
  WhiS[idx] = hi;
  WloS[idx] = (h16)((v - (float)hi) * 4096.f);
}

// x (f32) -> xhi/xlo fp16 streams, same [n][t][k] layout
__global__ void k_xsplit(const float* __restrict__ x, h16* __restrict__ xhi,
                         h16* __restrict__ xlo) {
  size_t i = ((size_t)blockIdx.x * 256 + threadIdx.x) * 4;
  float4 v = *(const float4*)(x + i);
  union { h16 h[4]; uint2 u; } a, b;
  float vv[4] = {v.x, v.y, v.z, v.w};
#pragma unroll
  for (int e = 0; e < 4; ++e) {
    h16 hh = (h16)vv[e];
    a.h[e] = hh;
    b.h[e] = (h16)((vv[e] - (float)hh) * 4096.f);
  }
  *(uint2*)(xhi + i) = a.u;
  *(uint2*)(xlo + i) = b.u;
}

// h0 = c0 = mean_p A[n][k][p] (fp32) + fp16 hi/lo split
__global__ void k_init(const float* __restrict__ Af, float* __restrict__ h32,
                       h16* __restrict__ hhi, h16* __restrict__ hlo,
                       float* __restrict__ cst) {
  int idx = blockIdx.x * 256 + threadIdx.x;   // n*512 + k, 131072 total
  const float* ap = Af + (size_t)idx * 16;
  float s = 0.f;
#pragma unroll
  for (int p = 0; p < 16; ++p) s += ap[p];
  s *= 0.0625f;
  h32[idx] = s;   // time-buffer 0
  cst[idx] = s;
  h16 hh = (h16)s;
  hhi[idx] = hh;
  hlo[idx] = (h16)((s - (float)hh) * 4096.f);
}

// ---------------- Per-step kernel 1: scores -> softmax -> attn ----------------
// One block per batch row n. All fp32. Kernel boundary synchronizes with k_gemm.
__global__ __launch_bounds__(512) void k_phaseA(const float* __restrict__ Af,
                                                const float* __restrict__ h32,
                                                h16* __restrict__ ahiB,
                                                h16* __restrict__ aloB, int t) {
  __shared__ float SC[8192];    // [512][16]
  __shared__ float ared[512];   // [32][16]
  __shared__ float wlds[16];
  const int tid = threadIdx.x;
  const int n = blockIdx.x;

  float Areg[16];
  const f32x4* A4 = (const f32x4*)(Af + (size_t)n * 8192 + tid * 16);
#pragma unroll
  for (int q4 = 0; q4 < 4; ++q4) {
    f32x4 v = A4[q4];
#pragma unroll
    for (int e = 0; e < 4; ++e) Areg[q4 * 4 + e] = v[e];
  }
  float hk = h32[(size_t)(t & 1) * 131072 + (size_t)n * 512 + tid];  // k = tid
#pragma unroll
  for (int p = 0; p < 16; ++p) SC[tid * 16 + p] = hk * Areg[p];
  __syncthreads();
  {
    int seg = tid >> 4, pp = tid & 15;
    float s = 0.f;
#pragma unroll
    for (int q = 0; q < 16; ++q) s += SC[(seg * 16 + q) * 16 + pp];
    ared[seg * 16 + pp] = s;
  }
  __syncthreads();
  if (tid < 16) {
    float s = 0.f;
#pragma unroll
    for (int q = 0; q < 32; ++q) s += ared[q * 16 + tid];
    s *= 0.04419417382415922f;   // 1/sqrt(512)
    float m = s;
#pragma unroll
    for (int o = 8; o >= 1; o >>= 1) m = fmaxf(m, __shfl_xor(m, o, 16));
    float e = __expf(s - m);
    float se = e;
#pragma unroll
    for (int o = 8; o >= 1; o >>= 1) se += __shfl_xor(se, o, 16);
    wlds[tid] = e / se;
  }
  __syncthreads();
  float av = 0.f;
#pragma unroll
  for (int p = 0; p < 16; ++p) av += Areg[p] * wlds[p];
  h16 ah = (h16)av;
  ahiB[(size_t)n * 512 + tid] = ah;
  aloB[(size_t)n * 512 + tid] = (h16)((av - (float)ah) * 4096.f);
}

// ---------------- Per-step kernel 2: GEMM + gates + state update ----------------
// 256 blocks x 512 threads. bid -> (g,j) swizzled so the 8 W-slices a given XCD
// stages stay L2-resident across steps (XCD = bid%8 assumption, perf-only).
// Block (g,j): rows n0..n0+63 (n0=g*64), h-cols j*8..j*8+7 (x4 gates = 32 a-cols).
template<bool XPRE>
__global__ __launch_bounds__(512, 2) void k_gemm(
    const float* __restrict__ bv,
    const float* __restrict__ x, const h16* __restrict__ xhi, const h16* __restrict__ xlo,
    const h16* __restrict__ WhiS, const h16* __restrict__ WloS,
    float* __restrict__ h32, h16* __restrict__ hhi, h16* __restrict__ hlo,
    const h16* __restrict__ ahiB, const h16* __restrict__ aloB,
    float* __restrict__ cst, float* __restrict__ out, int t) {
  __shared__ f16x8 Wlds[6144];    // [ks 48][cf 2][l 64] b-frags of Whi : 98304 B
  __shared__ float P[4 * 2112];   // 4 slots of [64 rows][33] : 33792 B

  const int tid = threadIdx.x;
  const int l = tid & 63, wv = tid >> 6;
  const int bid = blockIdx.x;
  const int g = (bid >> 3) & 3;
  const int j = (bid & 7) * 8 + (bid >> 5);
  const int n0 = g * 64;
  const int rA = n0 + (l & 15);        // A-frag row base
  const int klane = (l >> 4) * 8;

  // Whi slice -> LDS
  {
    const uint4* src = (const uint4*)(WhiS + (size_t)j * 49152);
    uint4* dst = (uint4*)Wlds;
    for (int i = tid; i < 6144; i += 512) dst[i] = src[i];
  }
  const h16* wloJ = WloS + (size_t)j * 49152;

  const int rC = tid >> 3, qC = tid & 7;
  const int colC = j * 8 + qC;
  const float b_i = bv[colC], b_f = bv[512 + colC], b_o = bv[1024 + colC],
              b_g = bv[1536 + colC];

  const int rb = t & 1, wb = rb ^ 1;
  const h16* hhiR = hhi + (size_t)rb * 131072;
  const h16* hloR = hlo + (size_t)rb * 131072;
  __syncthreads();

  f32x4 acc1[4][2], acc2[4][2];
#pragma unroll
  for (int rt = 0; rt < 4; ++rt)
#pragma unroll
    for (int cf = 0; cf < 2; ++cf) {
      acc1[rt][cf] = (f32x4){0.f, 0.f, 0.f, 0.f};
      acc2[rt][cf] = (f32x4){0.f, 0.f, 0.f, 0.f};
    }

  auto kstep = [&](int ksg) {
    const f16x8 bh0 = Wlds[(ksg * 2 + 0) * 64 + l];
    const f16x8 bh1 = Wlds[(ksg * 2 + 1) * 64 + l];
    const f16x8 bl0 = *(const f16x8*)(wloJ + ((size_t)(ksg * 2 + 0) * 64 + l) * 8);
    const f16x8 bl1 = *(const f16x8*)(wloJ + ((size_t)(ksg * 2 + 1) * 64 + l) * 8);
    f16x8 Ah[4], Al[4];
    const int kg = ksg * 32;
    if (kg < 512) {
      const size_t base = ((size_t)rA * 128 + t) * 512 + kg + klane;
      if (XPRE) {
#pragma unroll
        for (int rt = 0; rt < 4; ++rt) {
          Ah[rt] = *(const f16x8*)(xhi + base + (size_t)rt * 1048576);
          Al[rt] = *(const f16x8*)(xlo + base + (size_t)rt * 1048576);
        }
      } else {
#pragma unroll
        for (int rt = 0; rt < 4; ++rt) {
          const float* xp = x + base + (size_t)rt * 1048576;
          f32x4 v0 = *(const f32x4*)xp, v1 = *(const f32x4*)(xp + 4);
          float vv[8] = {v0[0], v0[1], v0[2], v0[3], v1[0], v1[1], v1[2], v1[3]};
#pragma unroll
          for (int e = 0; e < 8; ++e) {
            h16 hh = (h16)vv[e];
            Ah[rt][e] = hh;
            Al[rt][e] = (h16)((vv[e] - (float)hh) * 4096.f);
          }
        }
      }
    } else if (kg < 1024) {
      const size_t base = (size_t)rA * 512 + (kg - 512) + klane;
#pragma unroll
      for (int rt = 0; rt < 4; ++rt) {
        Ah[rt] = *(const f16x8*)(hhiR + base + rt * 8192);
        Al[rt] = *(const f16x8*)(hloR + base + rt * 8192);
      }
    } else {
      const size_t base = (size_t)rA * 512 + (kg - 1024) + klane;
#pragma unroll
      for (int rt = 0; rt < 4; ++rt) {
        Ah[rt] = *(const f16x8*)(ahiB + base + rt * 8192);
        Al[rt] = *(const f16x8*)(aloB + base + rt * 8192);
      }
    }
#pragma unroll
    for (int rt = 0; rt < 4; ++rt) {
      acc1[rt][0] = __builtin_amdgcn_mfma_f32_16x16x32_f16(Ah[rt], bh0, acc1[rt][0], 0, 0, 0);
      acc1[rt][1] = __builtin_amdgcn_mfma_f32_16x16x32_f16(Ah[rt], bh1, acc1[rt][1], 0, 0, 0);
      acc2[rt][0] = __builtin_amdgcn_mfma_f32_16x16x32_f16(Al[rt], bh0, acc2[rt][0], 0, 0, 0);
      acc2[rt][1] = __builtin_amdgcn_mfma_f32_16x16x32_f16(Al[rt], bh1, acc2[rt][1], 0, 0, 0);
      acc2[rt][0] = __builtin_amdgcn_mfma_f32_16x16x32_f16(Ah[rt], bl0, acc2[rt][0], 0, 0, 0);
      acc2[rt][1] = __builtin_amdgcn_mfma_f32_16x16x32_f16(Ah[rt], bl1, acc2[rt][1], 0, 0, 0);
    }
  };

  // K coverage: ksg = wv + 8i, i = 0..5 -> all 48 k-groups (x, h, attn)
#pragma unroll
  for (int i = 0; i < 6; ++i) kstep(wv + 8 * i);

  // combine hi + 2^-12 * lo-cross
  float accf[4][2][4];
#pragma unroll
  for (int rt = 0; rt < 4; ++rt)
#pragma unroll
    for (int cf = 0; cf < 2; ++cf)
#pragma unroll
      for (int rg = 0; rg < 4; ++rg)
        accf[rt][cf][rg] = acc1[rt][cf][rg] + acc2[rt][cf][rg] * (1.f / 4096.f);

  auto publish = [&](int slot) {
#pragma unroll
    for (int rt = 0; rt < 4; ++rt)
#pragma unroll
      for (int cf = 0; cf < 2; ++cf)
#pragma unroll
        for (int rg = 0; rg < 4; ++rg)
          P[slot * 2112 + (rt * 16 + (l >> 4) * 4 + rg) * 33 + cf * 16 + (l & 15)] =
              accf[rt][cf][rg];
  };
  auto addin = [&](int slot) {
#pragma unroll
    for (int rt = 0; rt < 4; ++rt)
#pragma unroll
      for (int cf = 0; cf < 2; ++cf)
#pragma unroll
        for (int rg = 0; rg < 4; ++rg)
          accf[rt][cf][rg] +=
              P[slot * 2112 + (rt * 16 + (l >> 4) * 4 + rg) * 33 + cf * 16 + (l & 15)];
  };

  if (wv >= 4) publish(wv - 4);
  __syncthreads();
  if (wv < 4) addin(wv);
  if (wv == 2) publish(2);
  if (wv == 3) publish(3);
  __syncthreads();
  if (wv == 0) addin(2);
  if (wv == 1) { addin(3); publish(1); }
  __syncthreads();
  if (wv == 0) { addin(1); publish(0); }
  __syncthreads();

  // gates (fp32) + state update, all 512 threads
  {
    float ai = P[rC * 33 + qC] + b_i;
    float af_ = P[rC * 33 + 8 + qC] + b_f;
    float ao = P[rC * 33 + 16 + qC] + b_o;
    float ag = P[rC * 33 + 24 + qC] + b_g;
    float ig = sigm(ai), fg = sigm(af_), og = sigm(ao), gg = tanhf(ag);
    const size_t cix = (size_t)(n0 + rC) * 512 + colC;
    float c = cst[cix];
    float cn = fg * c + ig * gg;
    cst[cix] = cn;
    float hn = og * tanhf(cn);
    h32[(size_t)wb * 131072 + cix] = hn;
    h16 hh = (h16)hn;
    hhi[(size_t)wb * 131072 + cix] = hh;
    hlo[(size_t)wb * 131072 + cix] = (h16)((hn - (float)hh) * 4096.f);
    out[((size_t)(n0 + rC) * 128 + t) * 512 + colC] = hn;   // fp32 output
  }
}

// ---------------- Host launcher ----------------

extern "C" void kernel_launch(void* const* d_in, const int* in_sizes, int n_in,
                              void* d_out, int out_size, void* d_ws, size_t ws_size,
                              hipStream_t stream) {
  (void)in_sizes; (void)n_in; (void)out_size;
  const float* x   = (const float*)d_in[0];   // (256,128,512)
  const float* Af  = (const float*)d_in[1];   // (256,512,16)
  const float* Wx  = (const float*)d_in[2];   // (512,2048)
  const float* Wh  = (const float*)d_in[3];   // (512,2048)
  const float* Wat = (const float*)d_in[4];   // (512,2048)
  const float* bv  = (const float*)d_in[5];   // (2048,)
  float* out = (float*)d_out;                 // fp32 output (reference dtype)

  char* ws = (char*)d_ws;
  size_t off = 0;
  auto alloc = [&](size_t nb) {
    char* p = ws + off; off = (off + nb + 255) & ~(size_t)255; return p;
  };
  h16*   WhiS = (h16*)alloc(3145728ull * 2);
  h16*   WloS = (h16*)alloc(3145728ull * 2);
  float* h32  = (float*)alloc(262144ull * 4);
  h16*   hhi  = (h16*)alloc(262144ull * 2);
  h16*   hlo  = (h16*)alloc(262144ull * 2);
  h16*   ahiB = (h16*)alloc(131072ull * 2);
  h16*   aloB = (h16*)alloc(131072ull * 2);
  float* cst  = (float*)alloc(131072ull * 4);
  size_t base_end = off;
  h16* xhi = (h16*)alloc(16777216ull * 2);
  h16* xlo = (h16*)alloc(16777216ull * 2);
  bool xpre = (ws_size >= base_end + 2ull * 16777216ull * 2 + 4096);

  k_pack_w<<<12288, 256, 0, stream>>>(Wx, Wh, Wat, WhiS, WloS);
  k_init<<<512, 256, 0, stream>>>(Af, h32, hhi, hlo, cst);
  if (xpre) k_xsplit<<<16384, 256, 0, stream>>>(x, xhi, xlo);

  for (int t = 0; t < 128; ++t) {
    k_phaseA<<<256, 512, 0, stream>>>(Af, h32, ahiB, aloB, t);
    if (xpre)
      k_gemm<true><<<256, 512, 0, stream>>>(bv, x, xhi, xlo, WhiS, WloS,
                                            h32, hhi, hlo, ahiB, aloB, cst, out, t);
    else
      k_gemm<false><<<256, 512, 0, stream>>>(bv, x, xhi, xlo, WhiS, WloS,
                                             h32, hhi, hlo, ahiB, aloB, cst, out, t);
  }
}

// Round 15
// 2769.252 us; speedup vs baseline: 1.8885x; 1.0574x over previous
//
#include <hip/hip_runtime.h>
#include <math.h>

typedef unsigned short u16;
typedef _Float16 h16;
typedef _Float16 f16x8 __attribute__((ext_vector_type(8)));
typedef float f32x4 __attribute__((ext_vector_type(4)));

__device__ __forceinline__ float sigm(float x) { return 1.f / (1.f + expf(-x)); }

// ---------------- Prologue kernels ----------------

// Pack W = [Wx;Wh;Wattn] (1536 x 2048 f32) into per-colblock f16 hi/lo MFMA
// b-frag streams. Layout: [j 0..64)[ks 0..48)[cf 0..2)[l 0..64)[e 0..8)
// element = W[k = ks*32 + (l>>4)*8 + e][acol], acol = (c32>>3)*512 + j*8 + (c32&7),
// c32 = cf*16 + (l&15).  lo scaled by 2^12 (exact) to stay in fp16 normal range.
__global__ void k_pack_w(const float* __restrict__ Wx, const float* __restrict__ Wh,
                         const float* __restrict__ Wat,
                         h16* __restrict__ WhiS, h16* __restrict__ WloS) {
  unsigned idx = blockIdx.x * 256 + threadIdx.x;   // 0..3145727
  unsigned e = idx & 7, l = (idx >> 3) & 63, cf = (idx >> 9) & 1;
  unsigned t2 = idx >> 10;
  unsigned j = t2 / 48u, ks = t2 - j * 48u;
  unsigned k = ks * 32 + ((l >> 4) << 3) + e;
  unsigned c32 = cf * 16 + (l & 15);
  unsigned acol = (c32 >> 3) * 512 + j * 8 + (c32 & 7);
  float v = (k < 512) ? Wx[(size_t)k * 2048 + acol]
          : (k < 1024) ? Wh[(size_t)(k - 512) * 2048 + acol]
                       : Wat[(size_t)(k - 1024) * 2048 + acol];
  h16 hi = (h16)v;
  WhiS[idx] = hi;
  WloS[idx] = (h16)((v - (float)hi) * 4096.f);
}

// x (f32) -> xhi/xlo fp16 streams, same [n][t][k] layout
__global__ void k_xsplit(const float* __restrict__ x, h16* __restrict__ xhi,
                         h16* __restrict__ xlo) {
  size_t i = ((size_t)blockIdx.x * 256 + threadIdx.x) * 4;
  float4 v = *(const float4*)(x + i);
  union { h16 h[4]; uint2 u; } a, b;
  float vv[4] = {v.x, v.y, v.z, v.w};
#pragma unroll
  for (int e = 0; e < 4; ++e) {
    h16 hh = (h16)vv[e];
    a.h[e] = hh;
    b.h[e] = (h16)((vv[e] - (float)hh) * 4096.f);
  }
  *(uint2*)(xhi + i) = a.u;
  *(uint2*)(xlo + i) = b.u;
}

// h0 = c0 = mean_p A[n][k][p] (fp32) + fp16 hi/lo split
__global__ void k_init(const float* __restrict__ Af, float* __restrict__ h32,
                       h16* __restrict__ hhi, h16* __restrict__ hlo,
                       float* __restrict__ cst) {
  int idx = blockIdx.x * 256 + threadIdx.x;   // n*512 + k, 131072 total
  const float* ap = Af + (size_t)idx * 16;
  float s = 0.f;
#pragma unroll
  for (int p = 0; p < 16; ++p) s += ap[p];
  s *= 0.0625f;
  h32[idx] = s;   // time-buffer 0
  cst[idx] = s;
  h16 hh = (h16)s;
  hhi[idx] = hh;
  hlo[idx] = (h16)((s - (float)hh) * 4096.f);
}

// ---------------- Per-step kernel 1: scores -> softmax -> attn ----------------
// One block per batch row n. All fp32. Kernel boundary synchronizes with k_gemm.
__global__ __launch_bounds__(512) void k_phaseA(const float* __restrict__ Af,
                                                const float* __restrict__ h32,
                                                h16* __restrict__ ahiB,
                                                h16* __restrict__ aloB, int t) {
  __shared__ float SC[8192];    // [512][16]
  __shared__ float ared[512];   // [32][16]
  __shared__ float wlds[16];
  const int tid = threadIdx.x;
  const int n = blockIdx.x;

  float Areg[16];
  const f32x4* A4 = (const f32x4*)(Af + (size_t)n * 8192 + tid * 16);
#pragma unroll
  for (int q4 = 0; q4 < 4; ++q4) {
    f32x4 v = A4[q4];
#pragma unroll
    for (int e = 0; e < 4; ++e) Areg[q4 * 4 + e] = v[e];
  }
  float hk = h32[(size_t)(t & 1) * 131072 + (size_t)n * 512 + tid];  // k = tid
#pragma unroll
  for (int p = 0; p < 16; ++p) SC[tid * 16 + p] = hk * Areg[p];
  __syncthreads();
  {
    int seg = tid >> 4, pp = tid & 15;
    float s = 0.f;
#pragma unroll
    for (int q = 0; q < 16; ++q) s += SC[(seg * 16 + q) * 16 + pp];
    ared[seg * 16 + pp] = s;
  }
  __syncthreads();
  if (tid < 16) {
    float s = 0.f;
#pragma unroll
    for (int q = 0; q < 32; ++q) s += ared[q * 16 + tid];
    s *= 0.04419417382415922f;   // 1/sqrt(512)
    float m = s;
#pragma unroll
    for (int o = 8; o >= 1; o >>= 1) m = fmaxf(m, __shfl_xor(m, o, 16));
    float e = __expf(s - m);
    float se = e;
#pragma unroll
    for (int o = 8; o >= 1; o >>= 1) se += __shfl_xor(se, o, 16);
    wlds[tid] = e / se;
  }
  __syncthreads();
  float av = 0.f;
#pragma unroll
  for (int p = 0; p < 16; ++p) av += Areg[p] * wlds[p];
  h16 ah = (h16)av;
  ahiB[(size_t)n * 512 + tid] = ah;
  aloB[(size_t)n * 512 + tid] = (h16)((av - (float)ah) * 4096.f);
}

// ---------------- Per-step kernel 2: GEMM + gates + state update ----------------
// 512 blocks x 512 threads, 2 blocks/CU (4 waves/SIMD for latency hiding).
// Block: g = bid>>6 (rows n0=g*32..+31), j = (bid&7)*8 + ((bid>>3)&7) (8 h-cols,
// XCD-pinned W slice: XCD = bid%8 sees only j in [8*xcd, 8*xcd+8) -> W L2-resident).
// B-fragments (Whi AND Wlo) read directly from global/L2 — each frag is used once
// per step, so LDS staging (R14 structure) bought nothing and cost a serial copy.
template<bool XPRE>
__global__ __launch_bounds__(512, 4) void k_gemm(
    const float* __restrict__ bv,
    const float* __restrict__ x, const h16* __restrict__ xhi, const h16* __restrict__ xlo,
    const h16* __restrict__ WhiS, const h16* __restrict__ WloS,
    float* __restrict__ h32, h16* __restrict__ hhi, h16* __restrict__ hlo,
    const h16* __restrict__ ahiB, const h16* __restrict__ aloB,
    float* __restrict__ cst, float* __restrict__ out, int t) {
  __shared__ float P[7 * 1056];   // 7 slots of [32 rows][33] : 29568 B

  const int tid = threadIdx.x;
  const int l = tid & 63, wv = tid >> 6;
  const int bid = blockIdx.x;
  const int g = bid >> 6;                          // 0..7
  const int j = (bid & 7) * 8 + ((bid >> 3) & 7);  // 0..63
  const int n0 = g * 32;
  const int rA = n0 + (l & 15);        // A-frag row base
  const int klane = (l >> 4) * 8;

  const h16* whiJ = WhiS + (size_t)j * 49152;
  const h16* wloJ = WloS + (size_t)j * 49152;

  const int rC = tid >> 3, qC = tid & 7;   // cell mapping (tid < 256 only)
  const int colC = j * 8 + qC;
  const float b_i = bv[colC], b_f = bv[512 + colC], b_o = bv[1024 + colC],
              b_g = bv[1536 + colC];

  const int rb = t & 1, wb = rb ^ 1;
  const h16* hhiR = hhi + (size_t)rb * 131072;
  const h16* hloR = hlo + (size_t)rb * 131072;

  f32x4 acc1[2][2], acc2[2][2];
#pragma unroll
  for (int rt = 0; rt < 2; ++rt)
#pragma unroll
    for (int cf = 0; cf < 2; ++cf) {
      acc1[rt][cf] = (f32x4){0.f, 0.f, 0.f, 0.f};
      acc2[rt][cf] = (f32x4){0.f, 0.f, 0.f, 0.f};
    }

  auto kstep = [&](int ksg) {
    const f16x8 bh0 = *(const f16x8*)(whiJ + ((size_t)(ksg * 2 + 0) * 64 + l) * 8);
    const f16x8 bh1 = *(const f16x8*)(whiJ + ((size_t)(ksg * 2 + 1) * 64 + l) * 8);
    const f16x8 bl0 = *(const f16x8*)(wloJ + ((size_t)(ksg * 2 + 0) * 64 + l) * 8);
    const f16x8 bl1 = *(const f16x8*)(wloJ + ((size_t)(ksg * 2 + 1) * 64 + l) * 8);
    f16x8 Ah[2], Al[2];
    const int kg = ksg * 32;
    if (kg < 512) {
      const size_t base = ((size_t)rA * 128 + t) * 512 + kg + klane;
      if (XPRE) {
#pragma unroll
        for (int rt = 0; rt < 2; ++rt) {
          Ah[rt] = *(const f16x8*)(xhi + base + (size_t)rt * 1048576);
          Al[rt] = *(const f16x8*)(xlo + base + (size_t)rt * 1048576);
        }
      } else {
#pragma unroll
        for (int rt = 0; rt < 2; ++rt) {
          const float* xp = x + base + (size_t)rt * 1048576;
          f32x4 v0 = *(const f32x4*)xp, v1 = *(const f32x4*)(xp + 4);
          float vv[8] = {v0[0], v0[1], v0[2], v0[3], v1[0], v1[1], v1[2], v1[3]};
#pragma unroll
          for (int e = 0; e < 8; ++e) {
            h16 hh = (h16)vv[e];
            Ah[rt][e] = hh;
            Al[rt][e] = (h16)((vv[e] - (float)hh) * 4096.f);
          }
        }
      }
    } else if (kg < 1024) {
      const size_t base = (size_t)rA * 512 + (kg - 512) + klane;
#pragma unroll
      for (int rt = 0; rt < 2; ++rt) {
        Ah[rt] = *(const f16x8*)(hhiR + base + rt * 8192);
        Al[rt] = *(const f16x8*)(hloR + base + rt * 8192);
      }
    } else {
      const size_t base = (size_t)rA * 512 + (kg - 1024) + klane;
#pragma unroll
      for (int rt = 0; rt < 2; ++rt) {
        Ah[rt] = *(const f16x8*)(ahiB + base + rt * 8192);
        Al[rt] = *(const f16x8*)(aloB + base + rt * 8192);
      }
    }
#pragma unroll
    for (int rt = 0; rt < 2; ++rt) {
      acc1[rt][0] = __builtin_amdgcn_mfma_f32_16x16x32_f16(Ah[rt], bh0, acc1[rt][0], 0, 0, 0);
      acc1[rt][1] = __builtin_amdgcn_mfma_f32_16x16x32_f16(Ah[rt], bh1, acc1[rt][1], 0, 0, 0);
      acc2[rt][0] = __builtin_amdgcn_mfma_f32_16x16x32_f16(Al[rt], bh0, acc2[rt][0], 0, 0, 0);
      acc2[rt][1] = __builtin_amdgcn_mfma_f32_16x16x32_f16(Al[rt], bh1, acc2[rt][1], 0, 0, 0);
      acc2[rt][0] = __builtin_amdgcn_mfma_f32_16x16x32_f16(Ah[rt], bl0, acc2[rt][0], 0, 0, 0);
      acc2[rt][1] = __builtin_amdgcn_mfma_f32_16x16x32_f16(Ah[rt], bl1, acc2[rt][1], 0, 0, 0);
    }
  };

  // K coverage: ksg = wv + 8i, i = 0..5 -> all 48 k-groups (x, h, attn)
#pragma unroll
  for (int i = 0; i < 6; ++i) kstep(wv + 8 * i);

  // combine hi + 2^-12 * lo-cross
  float accf[2][2][4];
#pragma unroll
  for (int rt = 0; rt < 2; ++rt)
#pragma unroll
    for (int cf = 0; cf < 2; ++cf)
#pragma unroll
      for (int rg = 0; rg < 4; ++rg)
        accf[rt][cf][rg] = acc1[rt][cf][rg] + acc2[rt][cf][rg] * (1.f / 4096.f);

  auto publish = [&](int slot) {
#pragma unroll
    for (int rt = 0; rt < 2; ++rt)
#pragma unroll
      for (int cf = 0; cf < 2; ++cf)
#pragma unroll
        for (int rg = 0; rg < 4; ++rg)
          P[slot * 1056 + (rt * 16 + (l >> 4) * 4 + rg) * 33 + cf * 16 + (l & 15)] =
              accf[rt][cf][rg];
  };
  auto addin = [&](int slot) {
#pragma unroll
    for (int rt = 0; rt < 2; ++rt)
#pragma unroll
      for (int cf = 0; cf < 2; ++cf)
#pragma unroll
        for (int rg = 0; rg < 4; ++rg)
          accf[rt][cf][rg] +=
              P[slot * 1056 + (rt * 16 + (l >> 4) * 4 + rg) * 33 + cf * 16 + (l & 15)];
  };

  // 8-wave reduction tree: 8 -> 4 -> 2 -> 1 copies, then final publish to slot 0
  if (wv >= 4) publish(wv - 4);
  __syncthreads();
  if (wv < 4) addin(wv);
  if (wv == 2) publish(4);
  if (wv == 3) publish(5);
  __syncthreads();
  if (wv == 0) addin(4);
  if (wv == 1) { addin(5); publish(6); }
  __syncthreads();
  if (wv == 0) { addin(6); publish(0); }
  __syncthreads();

  // gates (fp32) + state update: 256 threads cover 32 rows x 8 h-cols
  if (tid < 256) {
    float ai = P[rC * 33 + qC] + b_i;
    float af_ = P[rC * 33 + 8 + qC] + b_f;
    float ao = P[rC * 33 + 16 + qC] + b_o;
    float ag = P[rC * 33 + 24 + qC] + b_g;
    float ig = sigm(ai), fg = sigm(af_), og = sigm(ao), gg = tanhf(ag);
    const size_t cix = (size_t)(n0 + rC) * 512 + colC;
    float c = cst[cix];
    float cn = fg * c + ig * gg;
    cst[cix] = cn;
    float hn = og * tanhf(cn);
    h32[(size_t)wb * 131072 + cix] = hn;
    h16 hh = (h16)hn;
    hhi[(size_t)wb * 131072 + cix] = hh;
    hlo[(size_t)wb * 131072 + cix] = (h16)((hn - (float)hh) * 4096.f);
    out[((size_t)(n0 + rC) * 128 + t) * 512 + colC] = hn;   // fp32 output
  }
}

// ---------------- Host launcher ----------------

extern "C" void kernel_launch(void* const* d_in, const int* in_sizes, int n_in,
                              void* d_out, int out_size, void* d_ws, size_t ws_size,
                              hipStream_t stream) {
  (void)in_sizes; (void)n_in; (void)out_size;
  const float* x   = (const float*)d_in[0];   // (256,128,512)
  const float* Af  = (const float*)d_in[1];   // (256,512,16)
  const float* Wx  = (const float*)d_in[2];   // (512,2048)
  const float* Wh  = (const float*)d_in[3];   // (512,2048)
  const float* Wat = (const float*)d_in[4];   // (512,2048)
  const float* bv  = (const float*)d_in[5];   // (2048,)
  float* out = (float*)d_out;                 // fp32 output (reference dtype)

  char* ws = (char*)d_ws;
  size_t off = 0;
  auto alloc = [&](size_t nb) {
    char* p = ws + off; off = (off + nb + 255) & ~(size_t)255; return p;
  };
  h16*   WhiS = (h16*)alloc(3145728ull * 2);
  h16*   WloS = (h16*)alloc(3145728ull * 2);
  float* h32  = (float*)alloc(262144ull * 4);
  h16*   hhi  = (h16*)alloc(262144ull * 2);
  h16*   hlo  = (h16*)alloc(262144ull * 2);
  h16*   ahiB = (h16*)alloc(131072ull * 2);
  h16*   aloB = (h16*)alloc(131072ull * 2);
  float* cst  = (float*)alloc(131072ull * 4);
  size_t base_end = off;
  h16* xhi = (h16*)alloc(16777216ull * 2);
  h16* xlo = (h16*)alloc(16777216ull * 2);
  bool xpre = (ws_size >= base_end + 2ull * 16777216ull * 2 + 4096);

  k_pack_w<<<12288, 256, 0, stream>>>(Wx, Wh, Wat, WhiS, WloS);
  k_init<<<512, 256, 0, stream>>>(Af, h32, hhi, hlo, cst);
  if (xpre) k_xsplit<<<16384, 256, 0, stream>>>(x, xhi, xlo);

  for (int t = 0; t < 128; ++t) {
    k_phaseA<<<256, 512, 0, stream>>>(Af, h32, ahiB, aloB, t);
    if (xpre)
      k_gemm<true><<<512, 512, 0, stream>>>(bv, x, xhi, xlo, WhiS, WloS,
                                            h32, hhi, hlo, ahiB, aloB, cst, out, t);
    else
      k_gemm<false><<<512, 512, 0, stream>>>(bv, x, xhi, xlo, WhiS, WloS,
                                             h32, hhi, hlo, ahiB, aloB, cst, out, t);
  }
}